// Round 1
// baseline (75.399 us; speedup 1.0000x reference)
//
#include <hip/hip_runtime.h>
#include <stdint.h>

typedef uint16_t u16;
typedef __attribute__((ext_vector_type(4))) float f32x4;
typedef __attribute__((ext_vector_type(8))) short short8;
typedef __attribute__((ext_vector_type(4))) float float4v;
typedef __attribute__((ext_vector_type(4))) uint16_t u16x4;

#define DIMQ 1024
#define BATCH 8192
#define KDIM 1024
#define NDIM 1024

__device__ __forceinline__ u16 f2bf(float f) {
  uint32_t u = __float_as_uint(f);
  u += 0x7fffu + ((u >> 16) & 1u);
  return (u16)(u >> 16);
}

// complex 2x2 layout: {00r,00i, 01r,01i, 10r,10i, 11r,11i}
__device__ inline void cmul2x2(float* O, const float* A, const float* B) {
  for (int r = 0; r < 2; ++r)
    for (int c = 0; c < 2; ++c) {
      float re = 0.f, im = 0.f;
      for (int j = 0; j < 2; ++j) {
        float ar = A[(r*2+j)*2], ai = A[(r*2+j)*2+1];
        float br = B[(j*2+c)*2], bi = B[(j*2+c)*2+1];
        re += ar*br - ai*bi;
        im += ar*bi + ai*br;
      }
      O[(r*2+c)*2]   = re;
      O[(r*2+c)*2+1] = im;
    }
}
__device__ inline void mk_rx(float* m, float t) {
  float s, c; sincosf(0.5f*t, &s, &c);
  m[0]=c; m[1]=0; m[2]=0; m[3]=-s; m[4]=0; m[5]=-s; m[6]=c; m[7]=0;
}
__device__ inline void mk_ry(float* m, float t) {
  float s, c; sincosf(0.5f*t, &s, &c);
  m[0]=c; m[1]=0; m[2]=-s; m[3]=0; m[4]=s; m[5]=0; m[6]=c; m[7]=0;
}
__device__ inline void mk_rz(float* m, float t) {
  float s, c; sincosf(0.5f*t, &s, &c);
  m[0]=c; m[1]=-s; m[2]=0; m[3]=0; m[4]=0; m[5]=0; m[6]=c; m[7]=s;
}

// 50 fused 2x2 gates for the ADJOINT circuit, in applied order:
// stage 0 (i=0..9):   G_q = RY(-a)RZ(-b)RY(-c)  (adjoint of final RY,RZ,RY block)
// stage s=1..4 (i=10+ (s-1)*10 + q): layer l=4-s: H_q = RX(-x)RY(-y)RZ(-z)
__global__ void fuse_gates(const float* __restrict__ w, float* __restrict__ mats) {
  int i = threadIdx.x;
  if (i >= 50) return;
  float A[8], B[8], C[8], T[8], O[8];
  if (i < 10) {
    int q = i;
    mk_ry(A, -w[120 + q]);
    mk_rz(B, -w[130 + q]);
    mk_ry(C, -w[140 + q]);
  } else {
    int s = (i - 10) / 10, q = (i - 10) % 10;
    int l = 3 - s;
    mk_rx(A, -w[l*30 + q]);
    mk_ry(B, -w[l*30 + 10 + q]);
    mk_rz(C, -w[l*30 + 20 + q]);
  }
  cmul2x2(T, A, B);
  cmul2x2(O, T, C);
#pragma unroll
  for (int j = 0; j < 8; ++j) mats[i*8 + j] = O[j];
}

// One block per basis state d: simulate adjoint circuit on e_d in LDS,
// write row d of M = Re(U) as bf16 (coalesced).
__global__ __launch_bounds__(256) void build_M(const float* __restrict__ mats,
                                               u16* __restrict__ Bmat) {
  __shared__ float sr[DIMQ];
  __shared__ float si[DIMQ];
  __shared__ float gm[400];
  int t = threadIdx.x, d = blockIdx.x;
  for (int i = t; i < 400; i += 256) gm[i] = mats[i];
  for (int i = t; i < DIMQ; i += 256) { sr[i] = 0.f; si[i] = 0.f; }
  __syncthreads();
  if (t == 0) sr[d] = 1.0f;
  __syncthreads();

  for (int stage = 0; stage < 5; ++stage) {
    if (stage > 0) {
      // adjoint CNOT-ring permutation: s_new[x] = s_old[sigma(x)]
      float vr[4], vi[4];
#pragma unroll
      for (int j = 0; j < 4; ++j) {
        int x = t + j*256;
        int y = x;
        // evaluate inner-to-outer: C(0,1) map first (ctrl bit9 -> tgt bit8), ... then C(9,0) (ctrl bit0 -> tgt bit9)
#pragma unroll
        for (int qq = 0; qq < 9; ++qq) y ^= ((y >> (9 - qq)) & 1) << (8 - qq);
        y ^= (y & 1) << 9;
        vr[j] = sr[y]; vi[j] = si[y];
      }
      __syncthreads();
#pragma unroll
      for (int j = 0; j < 4; ++j) { sr[t + j*256] = vr[j]; si[t + j*256] = vi[j]; }
      __syncthreads();
    }
    for (int q = 0; q < 10; ++q) {
      const float* g = &gm[(stage*10 + q)*8];
      float u00r=g[0], u00i=g[1], u01r=g[2], u01i=g[3];
      float u10r=g[4], u10i=g[5], u11r=g[6], u11i=g[7];
      int p = 9 - q;  // qubit q lives at bit 9-q of the flat index
      for (int pp = t; pp < 512; pp += 256) {
        int i0 = ((pp >> p) << (p+1)) | (pp & ((1 << p) - 1));
        int i1 = i0 | (1 << p);
        float ar = sr[i0], ai = si[i0], br = sr[i1], bi = si[i1];
        sr[i0] = u00r*ar - u00i*ai + u01r*br - u01i*bi;
        si[i0] = u00r*ai + u00i*ar + u01r*bi + u01i*br;
        sr[i1] = u10r*ar - u10i*ai + u11r*br - u11i*bi;
        si[i1] = u10r*ai + u10i*ar + u11r*bi + u11i*br;
      }
      __syncthreads();
    }
  }
  for (int i = t; i < DIMQ; i += 256) Bmat[(size_t)d*DIMQ + i] = f2bf(sr[i]);
}

// Row-normalize x (fp32) -> bf16. One wave per row, 4 rows per block.
__global__ __launch_bounds__(256) void normalize_rows(const float* __restrict__ x,
                                                      u16* __restrict__ Abf) {
  int lane = threadIdx.x & 63, wave = threadIdx.x >> 6;
  int row = blockIdx.x * 4 + wave;
  const float* xr = x + (size_t)row * DIMQ;
  float4v v[4];
  float ss = 0.f;
#pragma unroll
  for (int j = 0; j < 4; ++j) {
    v[j] = *(const float4v*)(xr + j*256 + lane*4);
    ss += v[j][0]*v[j][0] + v[j][1]*v[j][1] + v[j][2]*v[j][2] + v[j][3]*v[j][3];
  }
#pragma unroll
  for (int off = 32; off; off >>= 1) ss += __shfl_xor(ss, off, 64);
  float inv = 1.0f / fmaxf(sqrtf(ss), 1e-12f);
  u16* orow = Abf + (size_t)row * DIMQ;
#pragma unroll
  for (int j = 0; j < 4; ++j) {
    u16x4 o;
#pragma unroll
    for (int e = 0; e < 4; ++e) o[e] = f2bf(v[j][e] * inv);
    *(u16x4*)(orow + j*256 + lane*4) = o;
  }
}

// C[8192,1024] = A[8192,1024] * B[1024,1024]^T   (bf16 in, fp32 out)
// 128x128 tile, BK=32, 4 waves (2x2 of 64x64), 16x16x32 bf16 MFMA,
// global_load_lds width-16 staging (m97 structure).
__global__ __launch_bounds__(256) void gemm_bt(const u16* __restrict__ A,
                                               const u16* __restrict__ Bm,
                                               float* __restrict__ C) {
  __shared__ u16 As[128*32];
  __shared__ u16 Bs[128*32];
  int t = threadIdx.x, lane = t & 63, wave = t >> 6;
  // XCD-aware swizzle: nwg=512, 512%8==0 -> nid=(bid%8)*64 + bid/8
  int bid = blockIdx.x;
  int nid = ((bid & 7) << 6) | (bid >> 3);
  int bm = nid >> 3, bn = nid & 7;
  size_t aBase = (size_t)bm * 128 * KDIM;
  size_t bBase = (size_t)bn * 128 * KDIM;
  int r0 = wave*16 + (lane >> 2);     // row within a 64-row chunk
  int c0 = (lane & 3) * 8;            // col (elements) within the 32-wide k-slab
  int wm = (wave >> 1) * 64, wn = (wave & 1) * 64;
  int la = lane & 15, lk = (lane >> 4) * 8;
  f32x4 acc[4][4];
#pragma unroll
  for (int m = 0; m < 4; ++m)
#pragma unroll
    for (int n = 0; n < 4; ++n) acc[m][n] = (f32x4){0.f, 0.f, 0.f, 0.f};

  for (int k0 = 0; k0 < KDIM; k0 += 32) {
    __syncthreads();
#pragma unroll
    for (int j = 0; j < 2; ++j) {
      __builtin_amdgcn_global_load_lds(
          (const __attribute__((address_space(1))) void*)(A + aBase + (size_t)(j*64 + r0)*KDIM + k0 + c0),
          (__attribute__((address_space(3))) void*)((char*)As + j*4096 + wave*1024), 16, 0, 0);
      __builtin_amdgcn_global_load_lds(
          (const __attribute__((address_space(1))) void*)(Bm + bBase + (size_t)(j*64 + r0)*KDIM + k0 + c0),
          (__attribute__((address_space(3))) void*)((char*)Bs + j*4096 + wave*1024), 16, 0, 0);
    }
    __syncthreads();
    short8 af[4], bf[4];
#pragma unroll
    for (int m = 0; m < 4; ++m) af[m] = *(const short8*)&As[(wm + m*16 + la)*32 + lk];
#pragma unroll
    for (int n = 0; n < 4; ++n) bf[n] = *(const short8*)&Bs[(wn + n*16 + la)*32 + lk];
#pragma unroll
    for (int m = 0; m < 4; ++m)
#pragma unroll
      for (int n = 0; n < 4; ++n)
        acc[m][n] = __builtin_amdgcn_mfma_f32_16x16x32_bf16(af[m], bf[n], acc[m][n], 0, 0, 0);
  }

  int orow0 = bm*128 + wm + (lane >> 4)*4;
  int ocol0 = bn*128 + wn + la;
#pragma unroll
  for (int m = 0; m < 4; ++m)
#pragma unroll
    for (int n = 0; n < 4; ++n)
#pragma unroll
      for (int j = 0; j < 4; ++j)
        C[(size_t)(orow0 + m*16 + j)*NDIM + ocol0 + n*16] = acc[m][n][j];
}

extern "C" void kernel_launch(void* const* d_in, const int* in_sizes, int n_in,
                              void* d_out, int out_size, void* d_ws, size_t ws_size,
                              hipStream_t stream) {
  const float* x = (const float*)d_in[0];
  const float* w = (const float*)d_in[1];
  float* out = (float*)d_out;
  char* ws = (char*)d_ws;
  float* mats = (float*)ws;                                  // 1600 B
  u16* Bmat   = (u16*)(ws + 4096);                           // 2 MB
  u16* Abf    = (u16*)(ws + 4096 + 2*1024*1024);             // 16 MB

  fuse_gates<<<1, 64, 0, stream>>>(w, mats);
  normalize_rows<<<BATCH/4, 256, 0, stream>>>(x, Abf);
  build_M<<<DIMQ, 256, 0, stream>>>(mats, Bmat);
  gemm_bt<<<(BATCH/128)*(NDIM/128), 256, 0, stream>>>(Abf, Bmat, out);
}